// Round 7
// baseline (639.265 us; speedup 1.0000x reference)
//
#include <hip/hip_runtime.h>
#include <math.h>

#define N_  32
#define C_  64
#define HW  192          // h == w == 192
#define NC  (N_ * C_)    // 2048 (n,c) tiles

__device__ __forceinline__ float wave_max(float v) {
#pragma unroll
    for (int off = 32; off; off >>= 1) v = fmaxf(v, __shfl_xor(v, off));
    return v;
}
__device__ __forceinline__ float wave_sum(float v) {
#pragma unroll
    for (int off = 32; off; off >>= 1) v += __shfl_xor(v, off);
    return v;
}

// 256-thread block reductions (4 waves), red[] is shared float[4]
__device__ __forceinline__ float block_max(float v, float* red) {
    const int w = threadIdx.x >> 6, lane = threadIdx.x & 63;
    v = wave_max(v);
    if (lane == 0) red[w] = v;
    __syncthreads();
    float r = fmaxf(fmaxf(red[0], red[1]), fmaxf(red[2], red[3]));
    __syncthreads();
    return r;
}
__device__ __forceinline__ float block_sum(float v, float* red) {
    const int w = threadIdx.x >> 6, lane = threadIdx.x & 63;
    v = wave_sum(v);
    if (lane == 0) red[w] = v;
    __syncthreads();
    float r = (red[0] + red[1]) + (red[2] + red[3]);
    __syncthreads();
    return r;
}

#define FMAX4(a, v)                                                    \
    do {                                                               \
        (a).x = fmaxf((a).x, (v).x); (a).y = fmaxf((a).y, (v).y);      \
        (a).z = fmaxf((a).z, (v).z); (a).w = fmaxf((a).w, (v).w);      \
    } while (0)

// One block per (n,c) tile. Tensors processed sequentially (halves register
// pressure); va/vb prefetch double-buffer keeps 6 float4 loads in flight.
// __launch_bounds__(256,4): allow up to 128 VGPR, 4 blocks/CU.
__global__ __launch_bounds__(256, 4) void k_stage1(const float* __restrict__ outp,
                                                   const float* __restrict__ tgtp,
                                                   float* __restrict__ simpos,
                                                   float* __restrict__ Aout) {
    __shared__ float4 cpart[4][8][6];  // 3 KB cross-wave colmax partials
    __shared__ float rowm[2][HW];
    __shared__ float colm[2][HW];
    __shared__ float A[4][HW];         // 0:Ao_h 1:Ao_w 2:At_h 3:At_w
    __shared__ float red[4];

    const int b    = blockIdx.x;
    const int tid  = threadIdx.x;
    const int j    = tid & 7;          // col-group within row (8 per row)
    const int r8   = tid >> 3;         // 0..31: row within pass
    const int w    = tid >> 6;
    const float NEG = -INFINITY;

    for (int t = 0; t < 2; ++t) {
        const float* X = (t == 0 ? outp : tgtp) + (size_t)b * (HW * HW);

        float4 cm[6];
#pragma unroll
        for (int k = 0; k < 6; ++k) cm[k] = make_float4(NEG, NEG, NEG, NEG);

        // prefetch p=0
        float4 va[6];
#pragma unroll
        for (int k = 0; k < 6; ++k)
            va[k] = ((const float4*)(X + r8 * HW))[j + 8 * k];

#pragma unroll
        for (int p = 0; p < 6; ++p) {
            float4 vb[6];
            if (p < 5) {
                const float4* rp = (const float4*)(X + (p * 32 + 32 + r8) * HW);
#pragma unroll
                for (int k = 0; k < 6; ++k) vb[k] = rp[j + 8 * k];
            }
            float rm = NEG;
#pragma unroll
            for (int k = 0; k < 6; ++k) {
                FMAX4(cm[k], va[k]);
                rm = fmaxf(rm, fmaxf(fmaxf(va[k].x, va[k].y),
                                     fmaxf(va[k].z, va[k].w)));
            }
            // row-max over the 8 col-group lanes (lane bits 0..2)
#pragma unroll
            for (int off = 1; off < 8; off <<= 1)
                rm = fmaxf(rm, __shfl_xor(rm, off));
            if (j == 0) rowm[t][p * 32 + r8] = rm;
#pragma unroll
            for (int k = 0; k < 6; ++k) va[k] = vb[k];
        }

        // col-max: reduce r within wave (lane bits 3..5 = stride 8,16,32)
#pragma unroll
        for (int off = 8; off < 64; off <<= 1) {
#pragma unroll
            for (int k = 0; k < 6; ++k) {
                float4 o;
                o.x = __shfl_xor(cm[k].x, off);
                o.y = __shfl_xor(cm[k].y, off);
                o.z = __shfl_xor(cm[k].z, off);
                o.w = __shfl_xor(cm[k].w, off);
                FMAX4(cm[k], o);
            }
        }
        __syncthreads();               // cpart reuse across t
        if ((tid & 63) < 8) {
#pragma unroll
            for (int k = 0; k < 6; ++k) cpart[w][j][k] = cm[k];
        }
        __syncthreads();
        if (tid < HW) {
            const int g = tid >> 2, comp = tid & 3;
            const int jj = g & 7, kk = g >> 3;
            float m = NEG;
#pragma unroll
            for (int ww = 0; ww < 4; ++ww)
                m = fmaxf(m, ((const float*)&cpart[ww][jj][kk])[comp]);
            colm[t][tid] = m;
        }
    }
    __syncthreads();

    // softmax + l2norm fused: a_i = exp(x_i - M) / ||exp(x - M)||
    // (softmax denominator cancels in cosine normalization; eps clamp inert)
    for (int v = 0; v < 4; ++v) {
        const float* src = (v == 0) ? rowm[0] : (v == 1) ? colm[0]
                         : (v == 2) ? rowm[1] : colm[1];
        float x = (tid < HW) ? src[tid] : NEG;
        float M = block_max(x, red);
        float e = (tid < HW) ? expf(x - M) : 0.0f;
        float ss = block_sum(e * e, red);
        if (tid < HW) A[v][tid] = e / sqrtf(ss);
    }
    __syncthreads();

    // sim_pos[b] = 0.5*(dot(Ao_h,At_h) + dot(Ao_w,At_w))
    float pd = (tid < HW) ? (A[0][tid] * A[2][tid] + A[1][tid] * A[3][tid]) : 0.0f;
    float sp = block_sum(pd, red);
    if (tid == 0) simpos[b] = 0.5f * sp;

    // store the 4 vectors (768 floats), coalesced
    float* dst = Aout + (size_t)b * 4 * HW;
    const float* Af = (const float*)A;
    for (int i = tid; i < 4 * HW; i += 256) dst[i] = Af[i];
}

// One block per n: channel-sum the A vectors, sim, loss.
__global__ __launch_bounds__(256) void k_stage2(const float* __restrict__ simpos,
                                                const float* __restrict__ Aout,
                                                float* __restrict__ loss) {
    __shared__ float S[4 * HW];
    __shared__ float red[4];
    const int n = blockIdx.x, tid = threadIdx.x;
    const float* base = Aout + (size_t)n * C_ * 4 * HW;

    float a0 = 0.0f, a1 = 0.0f, a2 = 0.0f;
    for (int c = 0; c < C_; ++c) {
        const float* a = base + c * 4 * HW;
        a0 += a[tid];
        a1 += a[tid + 256];
        a2 += a[tid + 512];
    }
    S[tid] = a0; S[tid + 256] = a1; S[tid + 512] = a2;
    __syncthreads();

    // vec order per block: 0=Ao_h 1=Ao_w 2=At_h 3=At_w
    float p = 0.0f;
    if (tid < HW)
        p = S[0 * HW + tid] * S[2 * HW + tid] + S[1 * HW + tid] * S[3 * HW + tid];
    float sim = 0.5f * block_sum(p, red);

    if (tid < C_) {
        loss[n * C_ + tid] =
            -logf(simpos[n * C_ + tid] / sim) * (1.0f / (N_ * C_));
    }
}

extern "C" void kernel_launch(void* const* d_in, const int* in_sizes, int n_in,
                              void* d_out, int out_size, void* d_ws, size_t ws_size,
                              hipStream_t stream) {
    const float* outp = (const float*)d_in[0];
    const float* tgtp = (const float*)d_in[1];
    float* simpos = (float*)d_ws;              // NC floats
    float* Aout   = simpos + NC;               // NC*4*HW floats (~6.3 MB)
    float* lossp  = (float*)d_out;             // NC floats

    hipLaunchKernelGGL(k_stage1, dim3(NC), dim3(256), 0, stream,
                       outp, tgtp, simpos, Aout);
    hipLaunchKernelGGL(k_stage2, dim3(N_), dim3(256), 0, stream,
                       simpos, Aout, lossp);
}

// Round 8
// 577.020 us; speedup vs baseline: 1.1079x; 1.1079x over previous
//
#include <hip/hip_runtime.h>
#include <math.h>

#define N_  32
#define C_  64
#define HW  192          // h == w == 192
#define NC  (N_ * C_)    // 2048 (n,c) tiles

__device__ __forceinline__ float wave_max(float v) {
#pragma unroll
    for (int off = 32; off; off >>= 1) v = fmaxf(v, __shfl_xor(v, off));
    return v;
}
__device__ __forceinline__ float wave_sum(float v) {
#pragma unroll
    for (int off = 32; off; off >>= 1) v += __shfl_xor(v, off);
    return v;
}

// 256-thread block reductions (4 waves), red[] is shared float[4]
__device__ __forceinline__ float block_max(float v, float* red) {
    const int w = threadIdx.x >> 6, lane = threadIdx.x & 63;
    v = wave_max(v);
    if (lane == 0) red[w] = v;
    __syncthreads();
    float r = fmaxf(fmaxf(red[0], red[1]), fmaxf(red[2], red[3]));
    __syncthreads();
    return r;
}
__device__ __forceinline__ float block_sum(float v, float* red) {
    const int w = threadIdx.x >> 6, lane = threadIdx.x & 63;
    v = wave_sum(v);
    if (lane == 0) red[w] = v;
    __syncthreads();
    float r = (red[0] + red[1]) + (red[2] + red[3]);
    __syncthreads();
    return r;
}

#define FMAX4(a, v)                                                    \
    do {                                                               \
        (a).x = fmaxf((a).x, (v).x); (a).y = fmaxf((a).y, (v).y);      \
        (a).z = fmaxf((a).z, (v).z); (a).w = fmaxf((a).w, (v).w);      \
    } while (0)

// One block per (n,c) tile. Single-buffered passes: 6 independent float4
// loads issued back-to-back per pass (TLP across 32 waves/CU hides latency;
// grid = 2048 = exactly 8 blocks/CU). Live set ~60 VGPR — no spill.
// amdgpu_waves_per_eu(4,6): reg budget ~85 (spill headroom), floor 4 waves.
__global__ __launch_bounds__(256)
__attribute__((amdgpu_waves_per_eu(4, 6)))
void k_stage1(const float* __restrict__ outp,
              const float* __restrict__ tgtp,
              float* __restrict__ simpos,
              float* __restrict__ Aout) {
    __shared__ float4 cpart[4][8][6];  // 3 KB cross-wave colmax partials
    __shared__ float rowm[2][HW];
    __shared__ float colm[2][HW];
    __shared__ float A[4][HW];         // 0:Ao_h 1:Ao_w 2:At_h 3:At_w
    __shared__ float red[4];

    const int b    = blockIdx.x;
    const int tid  = threadIdx.x;
    const int j    = tid & 7;          // col-group within row (8 per row)
    const int r8   = tid >> 3;         // 0..31: row within pass
    const int w    = tid >> 6;
    const float NEG = -INFINITY;

#pragma unroll 1
    for (int t = 0; t < 2; ++t) {
        const float* X = (t == 0 ? outp : tgtp) + (size_t)b * (HW * HW);

        float4 cm[6];
#pragma unroll
        for (int k = 0; k < 6; ++k) cm[k] = make_float4(NEG, NEG, NEG, NEG);

#pragma unroll 1
        for (int p = 0; p < 6; ++p) {
            const float4* rp = (const float4*)(X + (p * 32 + r8) * HW);
            float4 va[6];
#pragma unroll
            for (int k = 0; k < 6; ++k) va[k] = rp[j + 8 * k];

            float rm = NEG;
#pragma unroll
            for (int k = 0; k < 6; ++k) {
                FMAX4(cm[k], va[k]);
                rm = fmaxf(rm, fmaxf(fmaxf(va[k].x, va[k].y),
                                     fmaxf(va[k].z, va[k].w)));
            }
            // row-max over the 8 col-group lanes (lane bits 0..2)
#pragma unroll
            for (int off = 1; off < 8; off <<= 1)
                rm = fmaxf(rm, __shfl_xor(rm, off));
            if (j == 0) rowm[t][p * 32 + r8] = rm;
        }

        // col-max: reduce r within wave (lane bits 3..5 = stride 8,16,32)
#pragma unroll
        for (int off = 8; off < 64; off <<= 1) {
#pragma unroll
            for (int k = 0; k < 6; ++k) {
                float4 o;
                o.x = __shfl_xor(cm[k].x, off);
                o.y = __shfl_xor(cm[k].y, off);
                o.z = __shfl_xor(cm[k].z, off);
                o.w = __shfl_xor(cm[k].w, off);
                FMAX4(cm[k], o);
            }
        }
        __syncthreads();               // cpart reuse across t
        if ((tid & 63) < 8) {
#pragma unroll
            for (int k = 0; k < 6; ++k) cpart[w][j][k] = cm[k];
        }
        __syncthreads();
        if (tid < HW) {
            const int g = tid >> 2, comp = tid & 3;
            const int jj = g & 7, kk = g >> 3;
            float m = NEG;
#pragma unroll
            for (int ww = 0; ww < 4; ++ww)
                m = fmaxf(m, ((const float*)&cpart[ww][jj][kk])[comp]);
            colm[t][tid] = m;
        }
    }
    __syncthreads();

    // softmax + l2norm fused: a_i = exp(x_i - M) / ||exp(x - M)||
    // (softmax denominator cancels in cosine normalization; eps clamp inert)
    for (int v = 0; v < 4; ++v) {
        const float* src = (v == 0) ? rowm[0] : (v == 1) ? colm[0]
                         : (v == 2) ? rowm[1] : colm[1];
        float x = (tid < HW) ? src[tid] : NEG;
        float M = block_max(x, red);
        float e = (tid < HW) ? expf(x - M) : 0.0f;
        float ss = block_sum(e * e, red);
        if (tid < HW) A[v][tid] = e / sqrtf(ss);
    }
    __syncthreads();

    // sim_pos[b] = 0.5*(dot(Ao_h,At_h) + dot(Ao_w,At_w))
    float pd = (tid < HW) ? (A[0][tid] * A[2][tid] + A[1][tid] * A[3][tid]) : 0.0f;
    float sp = block_sum(pd, red);
    if (tid == 0) simpos[b] = 0.5f * sp;

    // store the 4 vectors (768 floats), coalesced
    float* dst = Aout + (size_t)b * 4 * HW;
    const float* Af = (const float*)A;
    for (int i = tid; i < 4 * HW; i += 256) dst[i] = Af[i];
}

// One block per n: channel-sum the A vectors, sim, loss.
__global__ __launch_bounds__(256) void k_stage2(const float* __restrict__ simpos,
                                                const float* __restrict__ Aout,
                                                float* __restrict__ loss) {
    __shared__ float S[4 * HW];
    __shared__ float red[4];
    const int n = blockIdx.x, tid = threadIdx.x;
    const float* base = Aout + (size_t)n * C_ * 4 * HW;

    float a0 = 0.0f, a1 = 0.0f, a2 = 0.0f;
    for (int c = 0; c < C_; ++c) {
        const float* a = base + c * 4 * HW;
        a0 += a[tid];
        a1 += a[tid + 256];
        a2 += a[tid + 512];
    }
    S[tid] = a0; S[tid + 256] = a1; S[tid + 512] = a2;
    __syncthreads();

    // vec order per block: 0=Ao_h 1=Ao_w 2=At_h 3=At_w
    float p = 0.0f;
    if (tid < HW)
        p = S[0 * HW + tid] * S[2 * HW + tid] + S[1 * HW + tid] * S[3 * HW + tid];
    float sim = 0.5f * block_sum(p, red);

    if (tid < C_) {
        loss[n * C_ + tid] =
            -logf(simpos[n * C_ + tid] / sim) * (1.0f / (N_ * C_));
    }
}

extern "C" void kernel_launch(void* const* d_in, const int* in_sizes, int n_in,
                              void* d_out, int out_size, void* d_ws, size_t ws_size,
                              hipStream_t stream) {
    const float* outp = (const float*)d_in[0];
    const float* tgtp = (const float*)d_in[1];
    float* simpos = (float*)d_ws;              // NC floats
    float* Aout   = simpos + NC;               // NC*4*HW floats (~6.3 MB)
    float* lossp  = (float*)d_out;             // NC floats

    hipLaunchKernelGGL(k_stage1, dim3(NC), dim3(256), 0, stream,
                       outp, tgtp, simpos, Aout);
    hipLaunchKernelGGL(k_stage2, dim3(N_), dim3(256), 0, stream,
                       simpos, Aout, lossp);
}